// Round 13
// baseline (130.265 us; speedup 1.0000x reference)
//
#include <hip/hip_runtime.h>
#include <stdint.h>

// CausalMultiHeadSelfAttention: B=2, S=2048, D_MODEL=1024, H=16, DK=64
// I/O: f32 (+ int32 positions). Internal: bf16 MFMA, f32 accum.
// Pipeline: prep (tables + W cvt + X cvt, one launch) -> QKV gemm (BK=64,
//           swizzled LDS, RoPE fused into epilogue, 3 blocks/CU; V^T out;
//           Q pre-scaled 0.125*log2e) -> causal flash attn (128-row bands,
//           4 waves x 32 q-rows/wave as two 16-row sets SHARING K/V fragment
//           reads; LDS dbuf K/V, swapped QK^T, lane-local softmax with native
//           v_exp_f32, defer-max, setprio) -> out gemm (f32 out).
// Q,K live in d_out (consumed by flash before out_gemm overwrites).

typedef unsigned short u16;
typedef __bf16 bf16x8 __attribute__((ext_vector_type(8)));
typedef float f32x4 __attribute__((ext_vector_type(4)));
typedef u16 u16x4 __attribute__((ext_vector_type(4)));

#define LOG2E 1.44269504088896340736f
#define QSCALE (0.125f * LOG2E)   // folded into Q at the gemm epilogue

// native cast -> v_cvt_pk_bf16_f32 (RNE)
static __device__ __forceinline__ u16 f2bf(float f) {
  __bf16 b = (__bf16)f;
  return __builtin_bit_cast(u16, b);
}

// native v_exp_f32 (2^x), bypassing the OCML accuracy wrapper.
extern "C" __device__ float __ocml_native_exp2_f32(float);
static __device__ __forceinline__ float fexp2(float x) {
#if __has_builtin(__builtin_amdgcn_exp2f)
  return __builtin_amdgcn_exp2f(x);
#else
  return __ocml_native_exp2_f32(x);
#endif
}

template<bool F32>
static __device__ __forceinline__ bf16x8 load8(const void* p, size_t off) {
  if constexpr (F32) {
    const float* f = (const float*)p + off;
    f32x4 a = *(const f32x4*)f;
    f32x4 b = *(const f32x4*)(f + 4);
    bf16x8 r;
    r[0] = (__bf16)a[0]; r[1] = (__bf16)a[1]; r[2] = (__bf16)a[2]; r[3] = (__bf16)a[3];
    r[4] = (__bf16)b[0]; r[5] = (__bf16)b[1]; r[6] = (__bf16)b[2]; r[7] = (__bf16)b[3];
    return r;
  } else {
    return *(const bf16x8*)((const u16*)p + off);
  }
}

// async global(16B/lane) -> LDS; dest must be wave-uniform base + lane*16.
static __device__ __forceinline__ void glds16(const u16* g, u16* l) {
  __builtin_amdgcn_global_load_lds(
      (const __attribute__((address_space(1))) unsigned int*)g,
      (__attribute__((address_space(3))) unsigned int*)l, 16, 0, 0);
}

// ------------------------------------------------- prep: tables + W cvt + X cvt
// z=0..3: weight matrix f32->bf16; z=4: rope cos/sin tables; z>=5: X chunks.
__global__ void prep_kernel(const float* __restrict__ Wq, const float* __restrict__ Wk,
                            const float* __restrict__ Wv, const float* __restrict__ Wo,
                            u16* __restrict__ wout,
                            const float* __restrict__ x, u16* __restrict__ xout,
                            size_t xn8,
                            const int* __restrict__ tp,
                            float* __restrict__ cosT, float* __restrict__ sinT) {
  const int z = blockIdx.z;
  const int i = blockIdx.x * 256 + threadIdx.x;     // 512 blocks x 256
  if (z == 4) {
    if (i >= 2048 * 32) return;
    int s = i >> 5, fi = i & 31;
    float p = (float)tp[s];
    float freq = powf(10000.0f, -(float)fi / 32.0f); // theta^(-2i/64)
    float ang = p * freq;
    cosT[i] = cosf(ang);
    sinT[i] = sinf(ang);
    return;
  }
  const float* src;
  u16* dst;
  size_t off;
  if (z < 4) {
    if (i >= 1024 * 1024 / 8) return;
    src = (z == 0) ? Wq : (z == 1) ? Wk : (z == 2) ? Wv : Wo;
    dst = wout + (size_t)z * 1024 * 1024;
    off = (size_t)i * 8;
  } else {
    size_t gi = (size_t)(z - 5) * (512 * 256) + i;
    if (gi >= xn8) return;
    src = x;
    dst = xout;
    off = gi * 8;
  }
  const float* p = src + off;
  f32x4 a = *(const f32x4*)p;
  f32x4 b = *(const f32x4*)(p + 4);
  bf16x8 r;
  r[0] = (__bf16)a[0]; r[1] = (__bf16)a[1]; r[2] = (__bf16)a[2]; r[3] = (__bf16)a[3];
  r[4] = (__bf16)b[0]; r[5] = (__bf16)b[1]; r[6] = (__bf16)b[2]; r[7] = (__bf16)b[3];
  *(bf16x8*)(dst + off) = r;
}

// ------------------------------------------------------ 128x128 gemm core, BK=64
// LDS tiles [128 rows][64 cols] with 16B-granule XOR swizzle:
// content[row][g] = global[row][g ^ (row&7)]; staging pre-swizzles the SOURCE
// granule (dest stays linear -> glds16-compatible); reads apply the same XOR.
template<bool AF32, bool BF32>
static __device__ __forceinline__ void gemm128_core(
    const void* __restrict__ A, const void* __restrict__ W,
    u16* As, u16* Bs, int m0, int n0, f32x4 (&acc)[4][4]) {
  const int tid = threadIdx.x;
  const int lane = tid & 63;
  const int wave = tid >> 6;
  const int wr = (wave >> 1) * 64, wc = (wave & 1) * 64;
  const int lr = lane & 15, lg = lane >> 4;
  const int srow = tid >> 3;                    // 0..31
  const int scol = ((tid & 7) ^ (srow & 7)) * 8;  // pre-swizzled src granule
  for (int k0 = 0; k0 < 1024; k0 += 64) {
    if constexpr (!AF32 && !BF32) {
      const u16* Ab = (const u16*)A;
      const u16* Wb = (const u16*)W;
      __syncthreads();   // previous iteration's LDS reads done
#pragma unroll
      for (int i = 0; i < 4; ++i) {
        glds16(Ab + (size_t)(m0 + srow + i * 32) * 1024 + k0 + scol, As + tid * 8 + i * 2048);
        glds16(Wb + (size_t)(n0 + srow + i * 32) * 1024 + k0 + scol, Bs + tid * 8 + i * 2048);
      }
      __syncthreads();   // vmcnt(0) drained before barrier -> data visible
    } else {
      bf16x8 ta[4], tb[4];
#pragma unroll
      for (int i = 0; i < 4; ++i) {
        ta[i] = load8<AF32>(A, (size_t)(m0 + srow + i * 32) * 1024 + k0 + scol);
        tb[i] = load8<BF32>(W, (size_t)(n0 + srow + i * 32) * 1024 + k0 + scol);
      }
      __syncthreads();
#pragma unroll
      for (int i = 0; i < 4; ++i) {
        *(bf16x8*)(As + tid * 8 + i * 2048) = ta[i];
        *(bf16x8*)(Bs + tid * 8 + i * 2048) = tb[i];
      }
      __syncthreads();
    }
#pragma unroll
    for (int kk = 0; kk < 2; ++kk) {
      bf16x8 af[4], bfr[4];
#pragma unroll
      for (int i = 0; i < 4; ++i) {
        const int ga = ((kk * 4 + lg) ^ (lr & 7)) * 8;
        af[i]  = *(const bf16x8*)(As + (wr + i * 16 + lr) * 64 + ga);
        bfr[i] = *(const bf16x8*)(Bs + (wc + i * 16 + lr) * 64 + ga);
      }
#pragma unroll
      for (int i = 0; i < 4; ++i)
#pragma unroll
        for (int j = 0; j < 4; ++j)
          acc[i][j] = __builtin_amdgcn_mfma_f32_16x16x32_bf16(af[i], bfr[j], acc[i][j], 0, 0, 0);
    }
  }
}

// ------------------------------------------------------------------ QKV gemm
// z=0: Q (rope+QSCALE) -> (B,H,S,64); z=1: K (rope) -> (B,H,S,64);
// z=2: V -> (B,H,64,S) transposed. RoPE fused via shfl_xor(v,1).
template<bool F32>
__global__ __launch_bounds__(256, 3)
void qkv_gemm_kernel(const void* __restrict__ X,
                     const void* __restrict__ Wq, const void* __restrict__ Wk,
                     const void* __restrict__ Wv,
                     const float* __restrict__ cosT, const float* __restrict__ sinT,
                     u16* __restrict__ Qo, u16* __restrict__ Ko, u16* __restrict__ Vto) {
  __shared__ __align__(16) u16 As[128 * 64];
  __shared__ __align__(16) u16 Bs[128 * 64];
  const int z = blockIdx.z;
  const void* W = (z == 0) ? Wq : ((z == 1) ? Wk : Wv);
  const int m0 = blockIdx.x * 128, n0 = blockIdx.y * 128;
  f32x4 acc[4][4] = {};
  gemm128_core<F32, F32>(X, W, As, Bs, m0, n0, acc);
  const int lane = threadIdx.x & 63, wave = threadIdx.x >> 6;
  const int wr = (wave >> 1) * 64, wc = (wave & 1) * 64;
  const int lr = lane & 15, lg = lane >> 4;
  if (z < 2) {
    u16* dst = z ? Ko : Qo;
    const float qs = z ? 1.0f : QSCALE;
    const int parity = lr & 1;
#pragma unroll
    for (int i = 0; i < 4; ++i) {
      const int rb = m0 + wr + i * 16 + lg * 4;  // global row = b*2048+s
#pragma unroll
      for (int n = 0; n < 4; ++n) {
        const int c = n0 + wc + n * 16 + lr;     // feature -> h,d
        const int hh = c >> 6, d = c & 63;
        const int ifr = d >> 1;                  // rope pair index 0..31
#pragma unroll
        for (int j = 0; j < 4; ++j) {
          const int r = rb + j;
          const int s = r & 2047;
          float v = acc[i][n][j];
          float p = __shfl_xor(v, 1);            // partner (other parity)
          float cs = cosT[s * 32 + ifr];
          float sn = sinT[s * 32 + ifr];
          float res = parity ? (p * sn + v * cs) : (v * cs - p * sn);
          dst[(((size_t)(r >> 11) * 16 + hh) * 2048 + s) * 64 + d] =
              f2bf(res * qs);
        }
      }
    }
  } else {  // V transposed: 4 consecutive rows (j) pack into one 8B store
#pragma unroll
    for (int i = 0; i < 4; ++i) {
      const int s0 = m0 + wr + i * 16 + lg * 4;
      const int bb = s0 >> 11, ss = s0 & 2047;
#pragma unroll
      for (int n = 0; n < 4; ++n) {
        const int c = n0 + wc + n * 16 + lr;
        const int hh = c >> 6, d = c & 63;
        u16x4 pk;
#pragma unroll
        for (int j = 0; j < 4; ++j) pk[j] = f2bf(acc[i][n][j]);
        *(u16x4*)(Vto + (((size_t)bb * 16 + hh) * 64 + d) * 2048 + ss) = pk;
      }
    }
  }
}

// ------------------------------------------------------------- flash attention
// softmax for one 16-row set: lane-local + 2 shfls, defer-max, rescale accO.
static __device__ __forceinline__ void softmax_rs(
    f32x4 (&s)[4], float& m, float& l, f32x4 (&accO)[4], u16x4 (&pk)[4]) {
  float t0 = fmaxf(fmaxf(s[0][0], s[0][1]), s[0][2]);
  float t1 = fmaxf(fmaxf(s[0][3], s[1][0]), s[1][1]);
  float t2 = fmaxf(fmaxf(s[1][2], s[1][3]), s[2][0]);
  float t3 = fmaxf(fmaxf(s[2][1], s[2][2]), s[2][3]);
  float t4 = fmaxf(fmaxf(s[3][0], s[3][1]), s[3][2]);
  float tm = fmaxf(fmaxf(t0, t1), fmaxf(fmaxf(t2, t3), fmaxf(t4, s[3][3])));
  tm = fmaxf(tm, __shfl_xor(tm, 16));
  tm = fmaxf(tm, __shfl_xor(tm, 32));
  float ssum = 0.f;
  if (__all(tm <= m + 8.0f)) {           // defer: keep old max, no rescale
#pragma unroll
    for (int n = 0; n < 4; ++n)
#pragma unroll
      for (int j = 0; j < 4; ++j) {
        float p = fexp2(s[n][j] - m);
        ssum += p;
        pk[n][j] = f2bf(p);
      }
    ssum += __shfl_xor(ssum, 16);
    ssum += __shfl_xor(ssum, 32);
    l += ssum;
  } else {
    const float mn = fmaxf(m, tm);
    const float al = fexp2(m - mn);
    m = mn;
#pragma unroll
    for (int n = 0; n < 4; ++n)
#pragma unroll
      for (int j = 0; j < 4; ++j) {
        float p = fexp2(s[n][j] - mn);
        ssum += p;
        pk[n][j] = f2bf(p);
      }
    ssum += __shfl_xor(ssum, 16);
    ssum += __shfl_xor(ssum, 32);
    l = l * al + ssum;
#pragma unroll
    for (int n = 0; n < 4; ++n)
#pragma unroll
      for (int j = 0; j < 4; ++j)
        accO[n][j] *= al;
  }
}

// One KV tile for a wave's TWO 16-row sets, sharing every K/V fragment read.
template<bool MASKED>
static __device__ __forceinline__ void attn_tile2(
    const u16* kb, const u16* vb, int kv0, int qr0, int qr1,
    const bf16x8 (&qf0)[2], const bf16x8 (&qf1)[2], u16* Psw,
    f32x4 (&accO0)[4], f32x4 (&accO1)[4],
    float& m0, float& l0, float& m1, float& l1, int lr, int lg) {
  f32x4 s0[4] = {}, s1[4] = {};
  __builtin_amdgcn_s_setprio(1);
#pragma unroll
  for (int n = 0; n < 4; ++n)
#pragma unroll
    for (int kk = 0; kk < 2; ++kk) {
      const int gsw = ((((kk << 2) | lg) ^ (lr & 7)) << 3);
      bf16x8 kf = *(const bf16x8*)&kb[(n * 16 + lr) * 64 + gsw];
      s0[n] = __builtin_amdgcn_mfma_f32_16x16x32_bf16(kf, qf0[kk], s0[n], 0, 0, 0);
      s1[n] = __builtin_amdgcn_mfma_f32_16x16x32_bf16(kf, qf1[kk], s1[n], 0, 0, 0);
    }
  __builtin_amdgcn_s_setprio(0);
  if (MASKED) {
#pragma unroll
    for (int n = 0; n < 4; ++n)
#pragma unroll
      for (int j = 0; j < 4; ++j) {
        const int c = kv0 + n * 16 + lg * 4 + j;
        if (c > qr0) s0[n][j] = -1e30f;
        if (c > qr1) s1[n][j] = -1e30f;
      }
  }
  u16x4 pk0[4], pk1[4];
  softmax_rs(s0, m0, l0, accO0, pk0);
  softmax_rs(s1, m1, l1, accO1, pk1);
  // P round-trips share the same per-wave LDS region (in-wave LDS ordering).
  bf16x8 pb0[2], pb1[2];
#pragma unroll
  for (int n = 0; n < 4; ++n) {
    const int g = n * 4 + lg;
    const int off = ((((g >> 1) ^ (lr & 7)) << 3) | ((g & 1) << 2));
    *(u16x4*)&Psw[lr * 64 + off] = pk0[n];
  }
#pragma unroll
  for (int kk = 0; kk < 2; ++kk) {
    const int po = (((kk * 4 + lg) ^ (lr & 7)) << 3);
    pb0[kk] = *(const bf16x8*)&Psw[lr * 64 + po];
  }
#pragma unroll
  for (int n = 0; n < 4; ++n) {
    const int g = n * 4 + lg;
    const int off = ((((g >> 1) ^ (lr & 7)) << 3) | ((g & 1) << 2));
    *(u16x4*)&Psw[lr * 64 + off] = pk1[n];
  }
#pragma unroll
  for (int kk = 0; kk < 2; ++kk) {
    const int po = (((kk * 4 + lg) ^ (lr & 7)) << 3);
    pb1[kk] = *(const bf16x8*)&Psw[lr * 64 + po];
  }
  __builtin_amdgcn_s_setprio(1);
#pragma unroll
  for (int kk = 0; kk < 2; ++kk) {
    const int gsw = ((((kk << 2) | lg) ^ (lr & 7)) << 3);
#pragma unroll
    for (int db = 0; db < 4; ++db) {
      bf16x8 vf = *(const bf16x8*)&vb[(db * 16 + lr) * 64 + gsw];
      accO0[db] = __builtin_amdgcn_mfma_f32_16x16x32_bf16(vf, pb0[kk], accO0[db], 0, 0, 0);
      accO1[db] = __builtin_amdgcn_mfma_f32_16x16x32_bf16(vf, pb1[kk], accO1[db], 0, 0, 0);
    }
  }
  __builtin_amdgcn_s_setprio(0);
}

// grid (B*16 heads, 16 bands of 128 rows, heavy-first), 256 thr = 4 waves.
// Wave owns 32 q-rows (two 16-row sets). Waves 0,1 skip the block's last
// tile (their rows end one 64-tile earlier) but still hit every barrier.
__global__ __launch_bounds__(256, 4)
void flash_attn_kernel(const u16* __restrict__ Q, const u16* __restrict__ K,
                       const u16* __restrict__ Vt, u16* __restrict__ O) {
  __shared__ __align__(16) u16 Klds[2][64 * 64];
  __shared__ __align__(16) u16 Vlds[2][64 * 64];
  __shared__ __align__(16) u16 Ps[4][16 * 64];
  const int bh = blockIdx.x;
  const int qcb = 15 - (int)blockIdx.y;    // heavy-first, 128-row bands
  const int b = bh >> 4, h = bh & 15;
  const int tid = threadIdx.x;
  const int wv = tid >> 6, lane = tid & 63;
  const int lr = lane & 15, lg = lane >> 4;
  const int qb = qcb * 128 + wv * 32;      // this wave's 32-row base
  const int qr0 = qb + lr;
  const int qr1 = qb + 16 + lr;
  const size_t hb = (size_t)bh * (2048 * 64);
  const u16* Qh = Q + hb;

  // staging pointers advanced incrementally; wave stages 16 rows of K + V.
  const int sgr = ((lane & 7) ^ (lane >> 3)) << 3;  // pre-swizzled src granule
  const int srw = lane >> 3;                        // 0..7
  const u16* kp = K + hb + (size_t)(wv * 16 + srw) * 64 + sgr;
  const u16* vp = Vt + hb + (size_t)(wv * 16 + srw) * 2048 + sgr;
  const int ldso = (wv * 16) * 64;
  auto STAGE = [&](const u16* kq, const u16* vq, int bufi) {
    u16* kbd = Klds[bufi] + ldso;
    u16* vbd = Vlds[bufi] + ldso;
    glds16(kq, kbd);
    glds16(kq + 8 * 64, kbd + 8 * 64);
    glds16(vq, vbd);
    glds16(vq + 8 * 2048, vbd + 8 * 64);
  };

  bf16x8 qf0[2], qf1[2];
#pragma unroll
  for (int kk = 0; kk < 2; ++kk) {
    qf0[kk] = *(const bf16x8*)(Qh + (size_t)qr0 * 64 + kk * 32 + lg * 8);
    qf1[kk] = *(const bf16x8*)(Qh + (size_t)qr1 * 64 + kk * 32 + lg * 8);
  }

  f32x4 accO0[4] = {}, accO1[4] = {};
  float m0 = -1e30f, l0 = 0.f, m1 = -1e30f, l1 = 0.f;

  const int ntb = 2 * qcb + 2;             // block trip count
  const int ntw = 2 * qcb + (wv >= 2 ? 1 : 0) + 1;  // this wave's trips
  STAGE(kp, vp, 0);
  kp += 64 * 64; vp += 64;
  __syncthreads();                         // drain stage-0, all waves ready
  for (int t = 0; t < ntb; ++t) {
    if (t + 1 < ntb) {
      STAGE(kp, vp, (t & 1) ^ 1);          // prefetch next into other buffer
      kp += 64 * 64; vp += 64;
    }
    if (t < ntw) {
      const u16* kb = Klds[t & 1];
      const u16* vb = Vlds[t & 1];
      if (t == ntw - 1)
        attn_tile2<true>(kb, vb, t * 64, qr0, qr1, qf0, qf1, Ps[wv],
                         accO0, accO1, m0, l0, m1, l1, lr, lg);
      else
        attn_tile2<false>(kb, vb, t * 64, qr0, qr1, qf0, qf1, Ps[wv],
                          accO0, accO1, m0, l0, m1, l1, lr, lg);
    }
    __syncthreads();                       // drain prefetch + lds reads
  }

  const float inv0 = 1.0f / l0, inv1 = 1.0f / l1;
#pragma unroll
  for (int db = 0; db < 4; ++db) {
    u16x4 w0, w1;
#pragma unroll
    for (int j = 0; j < 4; ++j) {
      w0[j] = f2bf(accO0[db][j] * inv0);
      w1[j] = f2bf(accO1[db][j] * inv1);
    }
    const int d = db * 16 + lg * 4;
    *(u16x4*)&O[((size_t)(b * 2048 + qr0) * 16 + h) * 64 + d] = w0;
    *(u16x4*)&O[((size_t)(b * 2048 + qr1) * 16 + h) * 64 + d] = w1;
  }
}

// ------------------------------------------------------------ output projection
template<bool WF32>
__global__ __launch_bounds__(256, 2)
void out_gemm_kernel(const u16* __restrict__ A, const void* __restrict__ W,
                     float* __restrict__ out) {
  __shared__ __align__(16) u16 As[128 * 64];
  __shared__ __align__(16) u16 Bs[128 * 64];
  const int m0 = blockIdx.x * 128, n0 = blockIdx.y * 128;
  f32x4 acc[4][4] = {};
  gemm128_core<false, WF32>(A, W, As, Bs, m0, n0, acc);
  const int lane = threadIdx.x & 63, wave = threadIdx.x >> 6;
  const int wr = (wave >> 1) * 64, wc = (wave & 1) * 64;
  const int lr = lane & 15, lg = lane >> 4;
#pragma unroll
  for (int i = 0; i < 4; ++i)
#pragma unroll
    for (int n = 0; n < 4; ++n) {
      const int c = n0 + wc + n * 16 + lr;
#pragma unroll
      for (int j = 0; j < 4; ++j) {
        const int r = m0 + wr + i * 16 + lg * 4 + j;
        out[(size_t)r * 1024 + c] = acc[i][n][j];   // f32 store, no rounding
      }
    }
}

// --------------------------------------------------------------------- launch
extern "C" void kernel_launch(void* const* d_in, const int* in_sizes, int n_in,
                              void* d_out, int out_size, void* d_ws, size_t ws_size,
                              hipStream_t stream) {
  const float* x  = (const float*)d_in[0];
  const int*   tp = (const int*)d_in[1];
  const float* Wq = (const float*)d_in[2];
  const float* Wk = (const float*)d_in[3];
  const float* Wv = (const float*)d_in[4];
  const float* Wo = (const float*)d_in[5];
  float* out = (float*)d_out;
  const int B = in_sizes[0] / (2048 * 1024);
  const size_t xel = (size_t)B * 2048 * 1024;        // X elements
  const size_t tsz = xel * sizeof(u16);              // 8MB @ B=2
  const size_t TBL = 2048 * 32 * 2 * sizeof(float);  // cos+sin tables
  // Q,K (bf16) live inside d_out (f32 out = 2*tsz bytes); consumed by flash
  // before out_gemm overwrites. Vt, Ob, tables (+ bf16 copies) in ws.
  u16* Qb = (u16*)d_out;
  u16* Kb = (u16*)((char*)d_out + tsz);
  char* ws = (char*)d_ws;
  u16* Vt = (u16*)(ws);
  u16* Ob = (u16*)(ws + tsz);
  float* cosT = (float*)(ws + 2 * tsz);
  float* sinT = cosT + 2048 * 32;
  u16* Xb  = (u16*)(ws + 2 * tsz + TBL);
  u16* Wb4 = Xb + xel;                               // Wq|Wk|Wv|Wo bf16
  const size_t need = 2 * tsz + TBL + tsz + 4 * (size_t)(1024 * 1024) * sizeof(u16);
  const bool cvt = ws_size >= need;
  const size_t xn8 = xel / 8;                        // 8-elem groups in X
  const int xplanes = (int)((xn8 + 512 * 256 - 1) / (512 * 256));

  if (cvt) {
    prep_kernel<<<dim3(512, 1, 5 + xplanes), dim3(256), 0, stream>>>(
        Wq, Wk, Wv, Wo, Wb4, x, Xb, xn8, tp, cosT, sinT);
    qkv_gemm_kernel<false><<<dim3(B * 16, 8, 3), dim3(256), 0, stream>>>(
        Xb, Wb4, Wb4 + 1024 * 1024, Wb4 + 2 * 1024 * 1024, cosT, sinT, Qb, Kb, Vt);
  } else {
    prep_kernel<<<dim3(512, 1, 5), dim3(256), 0, stream>>>(
        Wq, Wk, Wv, Wo, Wb4, x, Xb, 0, tp, cosT, sinT);  // tables via z=4
    qkv_gemm_kernel<true><<<dim3(B * 16, 8, 3), dim3(256), 0, stream>>>(
        x, Wq, Wk, Wv, cosT, sinT, Qb, Kb, Vt);
  }
  flash_attn_kernel<<<dim3(B * 16, 16), dim3(256), 0, stream>>>(Qb, Kb, Vt, Ob);
  if (cvt) {
    out_gemm_kernel<false><<<dim3(B * 16, 8), dim3(256), 0, stream>>>(
        Ob, Wb4 + 3 * 1024 * 1024, out);
  } else {
    out_gemm_kernel<true><<<dim3(B * 16, 8), dim3(256), 0, stream>>>(Ob, Wo, out);
  }
}

// Round 14
// 115.283 us; speedup vs baseline: 1.1300x; 1.1300x over previous
//
#include <hip/hip_runtime.h>
#include <stdint.h>

// CausalMultiHeadSelfAttention: B=2, S=2048, D_MODEL=1024, H=16, DK=64
// I/O: f32 (+ int32 positions). Internal: bf16 MFMA, f32 accum.
// Pipeline: prep (tables + W cvt + X cvt, one launch) -> QKV gemm (BK=64,
//           swizzled LDS, RoPE fused into epilogue, 3 blocks/CU; V^T out;
//           Q pre-scaled 0.125*log2e) -> causal flash attn (128-row bands,
//           4 waves x 32 q-rows/wave as two 16-row sets SHARING K/V fragment
//           reads; launch_bounds(256,2) so the allocator takes ~120 VGPR
//           instead of spilling at 64 (r8/r13 lesson); LDS dbuf K/V, swapped
//           QK^T, lane-local softmax w/ native v_exp_f32, defer-max, setprio)
//           -> out gemm (f32 out).
// Q,K live in d_out (consumed by flash before out_gemm overwrites).

typedef unsigned short u16;
typedef __bf16 bf16x8 __attribute__((ext_vector_type(8)));
typedef float f32x4 __attribute__((ext_vector_type(4)));
typedef u16 u16x4 __attribute__((ext_vector_type(4)));

#define LOG2E 1.44269504088896340736f
#define QSCALE (0.125f * LOG2E)   // folded into Q at the gemm epilogue

// native cast -> v_cvt_pk_bf16_f32 (RNE)
static __device__ __forceinline__ u16 f2bf(float f) {
  __bf16 b = (__bf16)f;
  return __builtin_bit_cast(u16, b);
}

// native v_exp_f32 (2^x), bypassing the OCML accuracy wrapper.
extern "C" __device__ float __ocml_native_exp2_f32(float);
static __device__ __forceinline__ float fexp2(float x) {
#if __has_builtin(__builtin_amdgcn_exp2f)
  return __builtin_amdgcn_exp2f(x);
#else
  return __ocml_native_exp2_f32(x);
#endif
}

template<bool F32>
static __device__ __forceinline__ bf16x8 load8(const void* p, size_t off) {
  if constexpr (F32) {
    const float* f = (const float*)p + off;
    f32x4 a = *(const f32x4*)f;
    f32x4 b = *(const f32x4*)(f + 4);
    bf16x8 r;
    r[0] = (__bf16)a[0]; r[1] = (__bf16)a[1]; r[2] = (__bf16)a[2]; r[3] = (__bf16)a[3];
    r[4] = (__bf16)b[0]; r[5] = (__bf16)b[1]; r[6] = (__bf16)b[2]; r[7] = (__bf16)b[3];
    return r;
  } else {
    return *(const bf16x8*)((const u16*)p + off);
  }
}

// async global(16B/lane) -> LDS; dest must be wave-uniform base + lane*16.
static __device__ __forceinline__ void glds16(const u16* g, u16* l) {
  __builtin_amdgcn_global_load_lds(
      (const __attribute__((address_space(1))) unsigned int*)g,
      (__attribute__((address_space(3))) unsigned int*)l, 16, 0, 0);
}

// ------------------------------------------------- prep: tables + W cvt + X cvt
// z=0..3: weight matrix f32->bf16; z=4: rope cos/sin tables; z>=5: X chunks.
__global__ void prep_kernel(const float* __restrict__ Wq, const float* __restrict__ Wk,
                            const float* __restrict__ Wv, const float* __restrict__ Wo,
                            u16* __restrict__ wout,
                            const float* __restrict__ x, u16* __restrict__ xout,
                            size_t xn8,
                            const int* __restrict__ tp,
                            float* __restrict__ cosT, float* __restrict__ sinT) {
  const int z = blockIdx.z;
  const int i = blockIdx.x * 256 + threadIdx.x;     // 512 blocks x 256
  if (z == 4) {
    if (i >= 2048 * 32) return;
    int s = i >> 5, fi = i & 31;
    float p = (float)tp[s];
    float freq = powf(10000.0f, -(float)fi / 32.0f); // theta^(-2i/64)
    float ang = p * freq;
    cosT[i] = cosf(ang);
    sinT[i] = sinf(ang);
    return;
  }
  const float* src;
  u16* dst;
  size_t off;
  if (z < 4) {
    if (i >= 1024 * 1024 / 8) return;
    src = (z == 0) ? Wq : (z == 1) ? Wk : (z == 2) ? Wv : Wo;
    dst = wout + (size_t)z * 1024 * 1024;
    off = (size_t)i * 8;
  } else {
    size_t gi = (size_t)(z - 5) * (512 * 256) + i;
    if (gi >= xn8) return;
    src = x;
    dst = xout;
    off = gi * 8;
  }
  const float* p = src + off;
  f32x4 a = *(const f32x4*)p;
  f32x4 b = *(const f32x4*)(p + 4);
  bf16x8 r;
  r[0] = (__bf16)a[0]; r[1] = (__bf16)a[1]; r[2] = (__bf16)a[2]; r[3] = (__bf16)a[3];
  r[4] = (__bf16)b[0]; r[5] = (__bf16)b[1]; r[6] = (__bf16)b[2]; r[7] = (__bf16)b[3];
  *(bf16x8*)(dst + off) = r;
}

// ------------------------------------------------------ 128x128 gemm core, BK=64
// LDS tiles [128 rows][64 cols] with 16B-granule XOR swizzle:
// content[row][g] = global[row][g ^ (row&7)]; staging pre-swizzles the SOURCE
// granule (dest stays linear -> glds16-compatible); reads apply the same XOR.
template<bool AF32, bool BF32>
static __device__ __forceinline__ void gemm128_core(
    const void* __restrict__ A, const void* __restrict__ W,
    u16* As, u16* Bs, int m0, int n0, f32x4 (&acc)[4][4]) {
  const int tid = threadIdx.x;
  const int lane = tid & 63;
  const int wave = tid >> 6;
  const int wr = (wave >> 1) * 64, wc = (wave & 1) * 64;
  const int lr = lane & 15, lg = lane >> 4;
  const int srow = tid >> 3;                    // 0..31
  const int scol = ((tid & 7) ^ (srow & 7)) * 8;  // pre-swizzled src granule
  for (int k0 = 0; k0 < 1024; k0 += 64) {
    if constexpr (!AF32 && !BF32) {
      const u16* Ab = (const u16*)A;
      const u16* Wb = (const u16*)W;
      __syncthreads();   // previous iteration's LDS reads done
#pragma unroll
      for (int i = 0; i < 4; ++i) {
        glds16(Ab + (size_t)(m0 + srow + i * 32) * 1024 + k0 + scol, As + tid * 8 + i * 2048);
        glds16(Wb + (size_t)(n0 + srow + i * 32) * 1024 + k0 + scol, Bs + tid * 8 + i * 2048);
      }
      __syncthreads();   // vmcnt(0) drained before barrier -> data visible
    } else {
      bf16x8 ta[4], tb[4];
#pragma unroll
      for (int i = 0; i < 4; ++i) {
        ta[i] = load8<AF32>(A, (size_t)(m0 + srow + i * 32) * 1024 + k0 + scol);
        tb[i] = load8<BF32>(W, (size_t)(n0 + srow + i * 32) * 1024 + k0 + scol);
      }
      __syncthreads();
#pragma unroll
      for (int i = 0; i < 4; ++i) {
        *(bf16x8*)(As + tid * 8 + i * 2048) = ta[i];
        *(bf16x8*)(Bs + tid * 8 + i * 2048) = tb[i];
      }
      __syncthreads();
    }
#pragma unroll
    for (int kk = 0; kk < 2; ++kk) {
      bf16x8 af[4], bfr[4];
#pragma unroll
      for (int i = 0; i < 4; ++i) {
        const int ga = ((kk * 4 + lg) ^ (lr & 7)) * 8;
        af[i]  = *(const bf16x8*)(As + (wr + i * 16 + lr) * 64 + ga);
        bfr[i] = *(const bf16x8*)(Bs + (wc + i * 16 + lr) * 64 + ga);
      }
#pragma unroll
      for (int i = 0; i < 4; ++i)
#pragma unroll
        for (int j = 0; j < 4; ++j)
          acc[i][j] = __builtin_amdgcn_mfma_f32_16x16x32_bf16(af[i], bfr[j], acc[i][j], 0, 0, 0);
    }
  }
}

// ------------------------------------------------------------------ QKV gemm
// z=0: Q (rope+QSCALE) -> (B,H,S,64); z=1: K (rope) -> (B,H,S,64);
// z=2: V -> (B,H,64,S) transposed. RoPE fused via shfl_xor(v,1).
template<bool F32>
__global__ __launch_bounds__(256, 3)
void qkv_gemm_kernel(const void* __restrict__ X,
                     const void* __restrict__ Wq, const void* __restrict__ Wk,
                     const void* __restrict__ Wv,
                     const float* __restrict__ cosT, const float* __restrict__ sinT,
                     u16* __restrict__ Qo, u16* __restrict__ Ko, u16* __restrict__ Vto) {
  __shared__ __align__(16) u16 As[128 * 64];
  __shared__ __align__(16) u16 Bs[128 * 64];
  const int z = blockIdx.z;
  const void* W = (z == 0) ? Wq : ((z == 1) ? Wk : Wv);
  const int m0 = blockIdx.x * 128, n0 = blockIdx.y * 128;
  f32x4 acc[4][4] = {};
  gemm128_core<F32, F32>(X, W, As, Bs, m0, n0, acc);
  const int lane = threadIdx.x & 63, wave = threadIdx.x >> 6;
  const int wr = (wave >> 1) * 64, wc = (wave & 1) * 64;
  const int lr = lane & 15, lg = lane >> 4;
  if (z < 2) {
    u16* dst = z ? Ko : Qo;
    const float qs = z ? 1.0f : QSCALE;
    const int parity = lr & 1;
#pragma unroll
    for (int i = 0; i < 4; ++i) {
      const int rb = m0 + wr + i * 16 + lg * 4;  // global row = b*2048+s
#pragma unroll
      for (int n = 0; n < 4; ++n) {
        const int c = n0 + wc + n * 16 + lr;     // feature -> h,d
        const int hh = c >> 6, d = c & 63;
        const int ifr = d >> 1;                  // rope pair index 0..31
#pragma unroll
        for (int j = 0; j < 4; ++j) {
          const int r = rb + j;
          const int s = r & 2047;
          float v = acc[i][n][j];
          float p = __shfl_xor(v, 1);            // partner (other parity)
          float cs = cosT[s * 32 + ifr];
          float sn = sinT[s * 32 + ifr];
          float res = parity ? (p * sn + v * cs) : (v * cs - p * sn);
          dst[(((size_t)(r >> 11) * 16 + hh) * 2048 + s) * 64 + d] =
              f2bf(res * qs);
        }
      }
    }
  } else {  // V transposed: 4 consecutive rows (j) pack into one 8B store
#pragma unroll
    for (int i = 0; i < 4; ++i) {
      const int s0 = m0 + wr + i * 16 + lg * 4;
      const int bb = s0 >> 11, ss = s0 & 2047;
#pragma unroll
      for (int n = 0; n < 4; ++n) {
        const int c = n0 + wc + n * 16 + lr;
        const int hh = c >> 6, d = c & 63;
        u16x4 pk;
#pragma unroll
        for (int j = 0; j < 4; ++j) pk[j] = f2bf(acc[i][n][j]);
        *(u16x4*)(Vto + (((size_t)bb * 16 + hh) * 64 + d) * 2048 + ss) = pk;
      }
    }
  }
}

// ------------------------------------------------------------- flash attention
// softmax for one 16-row set: lane-local + 2 shfls, defer-max, rescale accO.
static __device__ __forceinline__ void softmax_rs(
    f32x4 (&s)[4], float& m, float& l, f32x4 (&accO)[4], u16x4 (&pk)[4]) {
  float t0 = fmaxf(fmaxf(s[0][0], s[0][1]), s[0][2]);
  float t1 = fmaxf(fmaxf(s[0][3], s[1][0]), s[1][1]);
  float t2 = fmaxf(fmaxf(s[1][2], s[1][3]), s[2][0]);
  float t3 = fmaxf(fmaxf(s[2][1], s[2][2]), s[2][3]);
  float t4 = fmaxf(fmaxf(s[3][0], s[3][1]), s[3][2]);
  float tm = fmaxf(fmaxf(t0, t1), fmaxf(fmaxf(t2, t3), fmaxf(t4, s[3][3])));
  tm = fmaxf(tm, __shfl_xor(tm, 16));
  tm = fmaxf(tm, __shfl_xor(tm, 32));
  float ssum = 0.f;
  if (__all(tm <= m + 8.0f)) {           // defer: keep old max, no rescale
#pragma unroll
    for (int n = 0; n < 4; ++n)
#pragma unroll
      for (int j = 0; j < 4; ++j) {
        float p = fexp2(s[n][j] - m);
        ssum += p;
        pk[n][j] = f2bf(p);
      }
    ssum += __shfl_xor(ssum, 16);
    ssum += __shfl_xor(ssum, 32);
    l += ssum;
  } else {
    const float mn = fmaxf(m, tm);
    const float al = fexp2(m - mn);
    m = mn;
#pragma unroll
    for (int n = 0; n < 4; ++n)
#pragma unroll
      for (int j = 0; j < 4; ++j) {
        float p = fexp2(s[n][j] - mn);
        ssum += p;
        pk[n][j] = f2bf(p);
      }
    ssum += __shfl_xor(ssum, 16);
    ssum += __shfl_xor(ssum, 32);
    l = l * al + ssum;
#pragma unroll
    for (int n = 0; n < 4; ++n)
#pragma unroll
      for (int j = 0; j < 4; ++j)
        accO[n][j] *= al;
  }
}

// One KV tile for a wave's TWO 16-row sets, sharing every K/V fragment read.
// P round-trips interleaved with the softmaxes to shorten pk live ranges.
template<bool MASKED>
static __device__ __forceinline__ void attn_tile2(
    const u16* kb, const u16* vb, int kv0, int qr0, int qr1,
    const bf16x8 (&qf0)[2], const bf16x8 (&qf1)[2], u16* Psw,
    f32x4 (&accO0)[4], f32x4 (&accO1)[4],
    float& m0, float& l0, float& m1, float& l1, int lr, int lg) {
  f32x4 s0[4] = {}, s1[4] = {};
  __builtin_amdgcn_s_setprio(1);
#pragma unroll
  for (int n = 0; n < 4; ++n)
#pragma unroll
    for (int kk = 0; kk < 2; ++kk) {
      const int gsw = ((((kk << 2) | lg) ^ (lr & 7)) << 3);
      bf16x8 kf = *(const bf16x8*)&kb[(n * 16 + lr) * 64 + gsw];
      s0[n] = __builtin_amdgcn_mfma_f32_16x16x32_bf16(kf, qf0[kk], s0[n], 0, 0, 0);
      s1[n] = __builtin_amdgcn_mfma_f32_16x16x32_bf16(kf, qf1[kk], s1[n], 0, 0, 0);
    }
  __builtin_amdgcn_s_setprio(0);
  if (MASKED) {
#pragma unroll
    for (int n = 0; n < 4; ++n)
#pragma unroll
      for (int j = 0; j < 4; ++j) {
        const int c = kv0 + n * 16 + lg * 4 + j;
        if (c > qr0) s0[n][j] = -1e30f;
        if (c > qr1) s1[n][j] = -1e30f;
      }
  }
  bf16x8 pb0[2], pb1[2];
  {
    u16x4 pk[4];
    softmax_rs(s0, m0, l0, accO0, pk);
#pragma unroll
    for (int n = 0; n < 4; ++n) {
      const int g = n * 4 + lg;
      const int off = ((((g >> 1) ^ (lr & 7)) << 3) | ((g & 1) << 2));
      *(u16x4*)&Psw[lr * 64 + off] = pk[n];
    }
#pragma unroll
    for (int kk = 0; kk < 2; ++kk) {
      const int po = (((kk * 4 + lg) ^ (lr & 7)) << 3);
      pb0[kk] = *(const bf16x8*)&Psw[lr * 64 + po];
    }
  }
  {
    u16x4 pk[4];
    softmax_rs(s1, m1, l1, accO1, pk);
#pragma unroll
    for (int n = 0; n < 4; ++n) {
      const int g = n * 4 + lg;
      const int off = ((((g >> 1) ^ (lr & 7)) << 3) | ((g & 1) << 2));
      *(u16x4*)&Psw[lr * 64 + off] = pk[n];
    }
#pragma unroll
    for (int kk = 0; kk < 2; ++kk) {
      const int po = (((kk * 4 + lg) ^ (lr & 7)) << 3);
      pb1[kk] = *(const bf16x8*)&Psw[lr * 64 + po];
    }
  }
  __builtin_amdgcn_s_setprio(1);
#pragma unroll
  for (int kk = 0; kk < 2; ++kk) {
    const int gsw = ((((kk << 2) | lg) ^ (lr & 7)) << 3);
#pragma unroll
    for (int db = 0; db < 4; ++db) {
      bf16x8 vf = *(const bf16x8*)&vb[(db * 16 + lr) * 64 + gsw];
      accO0[db] = __builtin_amdgcn_mfma_f32_16x16x32_bf16(vf, pb0[kk], accO0[db], 0, 0, 0);
      accO1[db] = __builtin_amdgcn_mfma_f32_16x16x32_bf16(vf, pb1[kk], accO1[db], 0, 0, 0);
    }
  }
  __builtin_amdgcn_s_setprio(0);
}

// grid (B*16 heads, 16 bands of 128 rows, heavy-first), 256 thr = 4 waves.
// Wave owns 32 q-rows (two 16-row sets). Waves 0,1 skip the block's last
// tile but still hit every barrier. launch_bounds(256,2): allow the
// allocator ~256 VGPR so it does NOT spill (r8/r13: at the (256,4) target
// it pinned 64 VGPR and spilled ~20MB to scratch). If the final count stays
// <=128, runtime occupancy is still 4 blocks/CU.
__global__ __launch_bounds__(256, 2)
void flash_attn_kernel(const u16* __restrict__ Q, const u16* __restrict__ K,
                       const u16* __restrict__ Vt, u16* __restrict__ O) {
  __shared__ __align__(16) u16 Klds[2][64 * 64];
  __shared__ __align__(16) u16 Vlds[2][64 * 64];
  __shared__ __align__(16) u16 Ps[4][16 * 64];
  const int bh = blockIdx.x;
  const int qcb = 15 - (int)blockIdx.y;    // heavy-first, 128-row bands
  const int b = bh >> 4, h = bh & 15;
  const int tid = threadIdx.x;
  const int wv = tid >> 6, lane = tid & 63;
  const int lr = lane & 15, lg = lane >> 4;
  const int qb = qcb * 128 + wv * 32;      // this wave's 32-row base
  const int qr0 = qb + lr;
  const int qr1 = qb + 16 + lr;
  const size_t hb = (size_t)bh * (2048 * 64);
  const u16* Qh = Q + hb;

  // staging pointers advanced incrementally; wave stages 16 rows of K + V.
  const int sgr = ((lane & 7) ^ (lane >> 3)) << 3;  // pre-swizzled src granule
  const int srw = lane >> 3;                        // 0..7
  const u16* kp = K + hb + (size_t)(wv * 16 + srw) * 64 + sgr;
  const u16* vp = Vt + hb + (size_t)(wv * 16 + srw) * 2048 + sgr;
  const int ldso = (wv * 16) * 64;
  auto STAGE = [&](const u16* kq, const u16* vq, int bufi) {
    u16* kbd = Klds[bufi] + ldso;
    u16* vbd = Vlds[bufi] + ldso;
    glds16(kq, kbd);
    glds16(kq + 8 * 64, kbd + 8 * 64);
    glds16(vq, vbd);
    glds16(vq + 8 * 2048, vbd + 8 * 64);
  };

  bf16x8 qf0[2], qf1[2];
#pragma unroll
  for (int kk = 0; kk < 2; ++kk) {
    qf0[kk] = *(const bf16x8*)(Qh + (size_t)qr0 * 64 + kk * 32 + lg * 8);
    qf1[kk] = *(const bf16x8*)(Qh + (size_t)qr1 * 64 + kk * 32 + lg * 8);
  }

  f32x4 accO0[4] = {}, accO1[4] = {};
  float m0 = -1e30f, l0 = 0.f, m1 = -1e30f, l1 = 0.f;

  const int ntb = 2 * qcb + 2;             // block trip count
  const int ntw = 2 * qcb + (wv >= 2 ? 1 : 0) + 1;  // this wave's trips
  STAGE(kp, vp, 0);
  kp += 64 * 64; vp += 64;
  __syncthreads();                         // drain stage-0, all waves ready
  for (int t = 0; t < ntb; ++t) {
    if (t + 1 < ntb) {
      STAGE(kp, vp, (t & 1) ^ 1);          // prefetch next into other buffer
      kp += 64 * 64; vp += 64;
    }
    if (t < ntw) {
      const u16* kb = Klds[t & 1];
      const u16* vb = Vlds[t & 1];
      if (t == ntw - 1)
        attn_tile2<true>(kb, vb, t * 64, qr0, qr1, qf0, qf1, Ps[wv],
                         accO0, accO1, m0, l0, m1, l1, lr, lg);
      else
        attn_tile2<false>(kb, vb, t * 64, qr0, qr1, qf0, qf1, Ps[wv],
                          accO0, accO1, m0, l0, m1, l1, lr, lg);
    }
    __syncthreads();                       // drain prefetch + lds reads
  }

  const float inv0 = 1.0f / l0, inv1 = 1.0f / l1;
#pragma unroll
  for (int db = 0; db < 4; ++db) {
    u16x4 w0, w1;
#pragma unroll
    for (int j = 0; j < 4; ++j) {
      w0[j] = f2bf(accO0[db][j] * inv0);
      w1[j] = f2bf(accO1[db][j] * inv1);
    }
    const int d = db * 16 + lg * 4;
    *(u16x4*)&O[((size_t)(b * 2048 + qr0) * 16 + h) * 64 + d] = w0;
    *(u16x4*)&O[((size_t)(b * 2048 + qr1) * 16 + h) * 64 + d] = w1;
  }
}

// ------------------------------------------------------------ output projection
template<bool WF32>
__global__ __launch_bounds__(256, 2)
void out_gemm_kernel(const u16* __restrict__ A, const void* __restrict__ W,
                     float* __restrict__ out) {
  __shared__ __align__(16) u16 As[128 * 64];
  __shared__ __align__(16) u16 Bs[128 * 64];
  const int m0 = blockIdx.x * 128, n0 = blockIdx.y * 128;
  f32x4 acc[4][4] = {};
  gemm128_core<false, WF32>(A, W, As, Bs, m0, n0, acc);
  const int lane = threadIdx.x & 63, wave = threadIdx.x >> 6;
  const int wr = (wave >> 1) * 64, wc = (wave & 1) * 64;
  const int lr = lane & 15, lg = lane >> 4;
#pragma unroll
  for (int i = 0; i < 4; ++i)
#pragma unroll
    for (int n = 0; n < 4; ++n) {
      const int c = n0 + wc + n * 16 + lr;
#pragma unroll
      for (int j = 0; j < 4; ++j) {
        const int r = m0 + wr + i * 16 + lg * 4 + j;
        out[(size_t)r * 1024 + c] = acc[i][n][j];   // f32 store, no rounding
      }
    }
}

// --------------------------------------------------------------------- launch
extern "C" void kernel_launch(void* const* d_in, const int* in_sizes, int n_in,
                              void* d_out, int out_size, void* d_ws, size_t ws_size,
                              hipStream_t stream) {
  const float* x  = (const float*)d_in[0];
  const int*   tp = (const int*)d_in[1];
  const float* Wq = (const float*)d_in[2];
  const float* Wk = (const float*)d_in[3];
  const float* Wv = (const float*)d_in[4];
  const float* Wo = (const float*)d_in[5];
  float* out = (float*)d_out;
  const int B = in_sizes[0] / (2048 * 1024);
  const size_t xel = (size_t)B * 2048 * 1024;        // X elements
  const size_t tsz = xel * sizeof(u16);              // 8MB @ B=2
  const size_t TBL = 2048 * 32 * 2 * sizeof(float);  // cos+sin tables
  // Q,K (bf16) live inside d_out (f32 out = 2*tsz bytes); consumed by flash
  // before out_gemm overwrites. Vt, Ob, tables (+ bf16 copies) in ws.
  u16* Qb = (u16*)d_out;
  u16* Kb = (u16*)((char*)d_out + tsz);
  char* ws = (char*)d_ws;
  u16* Vt = (u16*)(ws);
  u16* Ob = (u16*)(ws + tsz);
  float* cosT = (float*)(ws + 2 * tsz);
  float* sinT = cosT + 2048 * 32;
  u16* Xb  = (u16*)(ws + 2 * tsz + TBL);
  u16* Wb4 = Xb + xel;                               // Wq|Wk|Wv|Wo bf16
  const size_t need = 2 * tsz + TBL + tsz + 4 * (size_t)(1024 * 1024) * sizeof(u16);
  const bool cvt = ws_size >= need;
  const size_t xn8 = xel / 8;                        // 8-elem groups in X
  const int xplanes = (int)((xn8 + 512 * 256 - 1) / (512 * 256));

  if (cvt) {
    prep_kernel<<<dim3(512, 1, 5 + xplanes), dim3(256), 0, stream>>>(
        Wq, Wk, Wv, Wo, Wb4, x, Xb, xn8, tp, cosT, sinT);
    qkv_gemm_kernel<false><<<dim3(B * 16, 8, 3), dim3(256), 0, stream>>>(
        Xb, Wb4, Wb4 + 1024 * 1024, Wb4 + 2 * 1024 * 1024, cosT, sinT, Qb, Kb, Vt);
  } else {
    prep_kernel<<<dim3(512, 1, 5), dim3(256), 0, stream>>>(
        Wq, Wk, Wv, Wo, Wb4, x, Xb, 0, tp, cosT, sinT);  // tables via z=4
    qkv_gemm_kernel<true><<<dim3(B * 16, 8, 3), dim3(256), 0, stream>>>(
        x, Wq, Wk, Wv, cosT, sinT, Qb, Kb, Vt);
  }
  flash_attn_kernel<<<dim3(B * 16, 16), dim3(256), 0, stream>>>(Qb, Kb, Vt, Ob);
  if (cvt) {
    out_gemm_kernel<false><<<dim3(B * 16, 8), dim3(256), 0, stream>>>(
        Ob, Wb4 + 3 * 1024 * 1024, out);
  } else {
    out_gemm_kernel<true><<<dim3(B * 16, 8), dim3(256), 0, stream>>>(Ob, Wo, out);
  }
}

// Round 15
// 103.015 us; speedup vs baseline: 1.2645x; 1.1191x over previous
//
#include <hip/hip_runtime.h>
#include <stdint.h>

// CausalMultiHeadSelfAttention: B=2, S=2048, D_MODEL=1024, H=16, DK=64
// I/O: f32 (+ int32 positions). Internal: bf16 MFMA, f32 accum.
// Pipeline: prep (tables + W cvt + X cvt, one launch) -> QKV gemm (BK=64,
//           swizzled LDS, RoPE fused into epilogue, 3 blocks/CU; V^T out;
//           Q pre-scaled 0.125*log2e) -> causal flash attn (r12 config:
//           64-row bands, 1024 blocks = 4/CU, 4 waves x 16 q-rows, LDS dbuf
//           K/V, swapped QK^T, lane-local softmax w/ native v_exp_f32,
//           defer-max, setprio) -> out gemm (f32 out).
// LAW (r8/r10/r13/r14): flash is residency-bound; every variant that halves
// blocks/CU (bigger bands / paired bands) regressed. Keep 1024 blocks @ 4/CU.
// Q,K live in d_out (consumed by flash before out_gemm overwrites).

typedef unsigned short u16;
typedef __bf16 bf16x8 __attribute__((ext_vector_type(8)));
typedef float f32x4 __attribute__((ext_vector_type(4)));
typedef u16 u16x4 __attribute__((ext_vector_type(4)));

#define LOG2E 1.44269504088896340736f
#define QSCALE (0.125f * LOG2E)   // folded into Q at the gemm epilogue

// native cast -> v_cvt_pk_bf16_f32 (RNE)
static __device__ __forceinline__ u16 f2bf(float f) {
  __bf16 b = (__bf16)f;
  return __builtin_bit_cast(u16, b);
}

// native v_exp_f32 (2^x), bypassing the OCML accuracy wrapper.
extern "C" __device__ float __ocml_native_exp2_f32(float);
static __device__ __forceinline__ float fexp2(float x) {
#if __has_builtin(__builtin_amdgcn_exp2f)
  return __builtin_amdgcn_exp2f(x);
#else
  return __ocml_native_exp2_f32(x);
#endif
}

template<bool F32>
static __device__ __forceinline__ bf16x8 load8(const void* p, size_t off) {
  if constexpr (F32) {
    const float* f = (const float*)p + off;
    f32x4 a = *(const f32x4*)f;
    f32x4 b = *(const f32x4*)(f + 4);
    bf16x8 r;
    r[0] = (__bf16)a[0]; r[1] = (__bf16)a[1]; r[2] = (__bf16)a[2]; r[3] = (__bf16)a[3];
    r[4] = (__bf16)b[0]; r[5] = (__bf16)b[1]; r[6] = (__bf16)b[2]; r[7] = (__bf16)b[3];
    return r;
  } else {
    return *(const bf16x8*)((const u16*)p + off);
  }
}

// async global(16B/lane) -> LDS; dest must be wave-uniform base + lane*16.
static __device__ __forceinline__ void glds16(const u16* g, u16* l) {
  __builtin_amdgcn_global_load_lds(
      (const __attribute__((address_space(1))) unsigned int*)g,
      (__attribute__((address_space(3))) unsigned int*)l, 16, 0, 0);
}

// ------------------------------------------------- prep: tables + W cvt + X cvt
// z=0..3: weight matrix f32->bf16; z=4: rope cos/sin tables; z>=5: X chunks.
__global__ void prep_kernel(const float* __restrict__ Wq, const float* __restrict__ Wk,
                            const float* __restrict__ Wv, const float* __restrict__ Wo,
                            u16* __restrict__ wout,
                            const float* __restrict__ x, u16* __restrict__ xout,
                            size_t xn8,
                            const int* __restrict__ tp,
                            float* __restrict__ cosT, float* __restrict__ sinT) {
  const int z = blockIdx.z;
  const int i = blockIdx.x * 256 + threadIdx.x;     // 512 blocks x 256
  if (z == 4) {
    if (i >= 2048 * 32) return;
    int s = i >> 5, fi = i & 31;
    float p = (float)tp[s];
    float freq = powf(10000.0f, -(float)fi / 32.0f); // theta^(-2i/64)
    float ang = p * freq;
    cosT[i] = cosf(ang);
    sinT[i] = sinf(ang);
    return;
  }
  const float* src;
  u16* dst;
  size_t off;
  if (z < 4) {
    if (i >= 1024 * 1024 / 8) return;
    src = (z == 0) ? Wq : (z == 1) ? Wk : (z == 2) ? Wv : Wo;
    dst = wout + (size_t)z * 1024 * 1024;
    off = (size_t)i * 8;
  } else {
    size_t gi = (size_t)(z - 5) * (512 * 256) + i;
    if (gi >= xn8) return;
    src = x;
    dst = xout;
    off = gi * 8;
  }
  const float* p = src + off;
  f32x4 a = *(const f32x4*)p;
  f32x4 b = *(const f32x4*)(p + 4);
  bf16x8 r;
  r[0] = (__bf16)a[0]; r[1] = (__bf16)a[1]; r[2] = (__bf16)a[2]; r[3] = (__bf16)a[3];
  r[4] = (__bf16)b[0]; r[5] = (__bf16)b[1]; r[6] = (__bf16)b[2]; r[7] = (__bf16)b[3];
  *(bf16x8*)(dst + off) = r;
}

// ------------------------------------------------------ 128x128 gemm core, BK=64
// LDS tiles [128 rows][64 cols] with 16B-granule XOR swizzle:
// content[row][g] = global[row][g ^ (row&7)]; staging pre-swizzles the SOURCE
// granule (dest stays linear -> glds16-compatible); reads apply the same XOR.
template<bool AF32, bool BF32>
static __device__ __forceinline__ void gemm128_core(
    const void* __restrict__ A, const void* __restrict__ W,
    u16* As, u16* Bs, int m0, int n0, f32x4 (&acc)[4][4]) {
  const int tid = threadIdx.x;
  const int lane = tid & 63;
  const int wave = tid >> 6;
  const int wr = (wave >> 1) * 64, wc = (wave & 1) * 64;
  const int lr = lane & 15, lg = lane >> 4;
  const int srow = tid >> 3;                    // 0..31
  const int scol = ((tid & 7) ^ (srow & 7)) * 8;  // pre-swizzled src granule
  for (int k0 = 0; k0 < 1024; k0 += 64) {
    if constexpr (!AF32 && !BF32) {
      const u16* Ab = (const u16*)A;
      const u16* Wb = (const u16*)W;
      __syncthreads();   // previous iteration's LDS reads done
#pragma unroll
      for (int i = 0; i < 4; ++i) {
        glds16(Ab + (size_t)(m0 + srow + i * 32) * 1024 + k0 + scol, As + tid * 8 + i * 2048);
        glds16(Wb + (size_t)(n0 + srow + i * 32) * 1024 + k0 + scol, Bs + tid * 8 + i * 2048);
      }
      __syncthreads();   // vmcnt(0) drained before barrier -> data visible
    } else {
      bf16x8 ta[4], tb[4];
#pragma unroll
      for (int i = 0; i < 4; ++i) {
        ta[i] = load8<AF32>(A, (size_t)(m0 + srow + i * 32) * 1024 + k0 + scol);
        tb[i] = load8<BF32>(W, (size_t)(n0 + srow + i * 32) * 1024 + k0 + scol);
      }
      __syncthreads();
#pragma unroll
      for (int i = 0; i < 4; ++i) {
        *(bf16x8*)(As + tid * 8 + i * 2048) = ta[i];
        *(bf16x8*)(Bs + tid * 8 + i * 2048) = tb[i];
      }
      __syncthreads();
    }
#pragma unroll
    for (int kk = 0; kk < 2; ++kk) {
      bf16x8 af[4], bfr[4];
#pragma unroll
      for (int i = 0; i < 4; ++i) {
        const int ga = ((kk * 4 + lg) ^ (lr & 7)) * 8;
        af[i]  = *(const bf16x8*)(As + (wr + i * 16 + lr) * 64 + ga);
        bfr[i] = *(const bf16x8*)(Bs + (wc + i * 16 + lr) * 64 + ga);
      }
#pragma unroll
      for (int i = 0; i < 4; ++i)
#pragma unroll
        for (int j = 0; j < 4; ++j)
          acc[i][j] = __builtin_amdgcn_mfma_f32_16x16x32_bf16(af[i], bfr[j], acc[i][j], 0, 0, 0);
    }
  }
}

// ------------------------------------------------------------------ QKV gemm
// z=0: Q (rope+QSCALE) -> (B,H,S,64); z=1: K (rope) -> (B,H,S,64);
// z=2: V -> (B,H,64,S) transposed. RoPE fused via shfl_xor(v,1).
template<bool F32>
__global__ __launch_bounds__(256, 3)
void qkv_gemm_kernel(const void* __restrict__ X,
                     const void* __restrict__ Wq, const void* __restrict__ Wk,
                     const void* __restrict__ Wv,
                     const float* __restrict__ cosT, const float* __restrict__ sinT,
                     u16* __restrict__ Qo, u16* __restrict__ Ko, u16* __restrict__ Vto) {
  __shared__ __align__(16) u16 As[128 * 64];
  __shared__ __align__(16) u16 Bs[128 * 64];
  const int z = blockIdx.z;
  const void* W = (z == 0) ? Wq : ((z == 1) ? Wk : Wv);
  const int m0 = blockIdx.x * 128, n0 = blockIdx.y * 128;
  f32x4 acc[4][4] = {};
  gemm128_core<F32, F32>(X, W, As, Bs, m0, n0, acc);
  const int lane = threadIdx.x & 63, wave = threadIdx.x >> 6;
  const int wr = (wave >> 1) * 64, wc = (wave & 1) * 64;
  const int lr = lane & 15, lg = lane >> 4;
  if (z < 2) {
    u16* dst = z ? Ko : Qo;
    const float qs = z ? 1.0f : QSCALE;
    const int parity = lr & 1;
#pragma unroll
    for (int i = 0; i < 4; ++i) {
      const int rb = m0 + wr + i * 16 + lg * 4;  // global row = b*2048+s
#pragma unroll
      for (int n = 0; n < 4; ++n) {
        const int c = n0 + wc + n * 16 + lr;     // feature -> h,d
        const int hh = c >> 6, d = c & 63;
        const int ifr = d >> 1;                  // rope pair index 0..31
#pragma unroll
        for (int j = 0; j < 4; ++j) {
          const int r = rb + j;
          const int s = r & 2047;
          float v = acc[i][n][j];
          float p = __shfl_xor(v, 1);            // partner (other parity)
          float cs = cosT[s * 32 + ifr];
          float sn = sinT[s * 32 + ifr];
          float res = parity ? (p * sn + v * cs) : (v * cs - p * sn);
          dst[(((size_t)(r >> 11) * 16 + hh) * 2048 + s) * 64 + d] =
              f2bf(res * qs);
        }
      }
    }
  } else {  // V transposed: 4 consecutive rows (j) pack into one 8B store
#pragma unroll
    for (int i = 0; i < 4; ++i) {
      const int s0 = m0 + wr + i * 16 + lg * 4;
      const int bb = s0 >> 11, ss = s0 & 2047;
#pragma unroll
      for (int n = 0; n < 4; ++n) {
        const int c = n0 + wc + n * 16 + lr;
        const int hh = c >> 6, d = c & 63;
        u16x4 pk;
#pragma unroll
        for (int j = 0; j < 4; ++j) pk[j] = f2bf(acc[i][n][j]);
        *(u16x4*)(Vto + (((size_t)bb * 16 + hh) * 64 + d) * 2048 + ss) = pk;
      }
    }
  }
}

// ------------------------------------------------------------- flash attention
// softmax for one 16-row set: lane-local + 2 shfls, defer-max, rescale accO.
static __device__ __forceinline__ void softmax_rs(
    f32x4 (&s)[4], float& m, float& l, f32x4 (&accO)[4], u16x4 (&pk)[4]) {
  float t0 = fmaxf(fmaxf(s[0][0], s[0][1]), s[0][2]);
  float t1 = fmaxf(fmaxf(s[0][3], s[1][0]), s[1][1]);
  float t2 = fmaxf(fmaxf(s[1][2], s[1][3]), s[2][0]);
  float t3 = fmaxf(fmaxf(s[2][1], s[2][2]), s[2][3]);
  float t4 = fmaxf(fmaxf(s[3][0], s[3][1]), s[3][2]);
  float tm = fmaxf(fmaxf(t0, t1), fmaxf(fmaxf(t2, t3), fmaxf(t4, s[3][3])));
  tm = fmaxf(tm, __shfl_xor(tm, 16));
  tm = fmaxf(tm, __shfl_xor(tm, 32));
  float ssum = 0.f;
  if (__all(tm <= m + 8.0f)) {           // defer: keep old max, no rescale
#pragma unroll
    for (int n = 0; n < 4; ++n)
#pragma unroll
      for (int j = 0; j < 4; ++j) {
        float p = fexp2(s[n][j] - m);
        ssum += p;
        pk[n][j] = f2bf(p);
      }
    ssum += __shfl_xor(ssum, 16);
    ssum += __shfl_xor(ssum, 32);
    l += ssum;
  } else {
    const float mn = fmaxf(m, tm);
    const float al = fexp2(m - mn);
    m = mn;
#pragma unroll
    for (int n = 0; n < 4; ++n)
#pragma unroll
      for (int j = 0; j < 4; ++j) {
        float p = fexp2(s[n][j] - mn);
        ssum += p;
        pk[n][j] = f2bf(p);
      }
    ssum += __shfl_xor(ssum, 16);
    ssum += __shfl_xor(ssum, 32);
    l = l * al + ssum;
#pragma unroll
    for (int n = 0; n < 4; ++n)
#pragma unroll
      for (int j = 0; j < 4; ++j)
        accO[n][j] *= al;
  }
}

// One KV tile for one wave (16 q-rows). Swapped QK^T; P via per-wave LDS.
template<bool MASKED>
static __device__ __forceinline__ void attn_tile(
    const u16* kb, const u16* vb, int kv0, int qrow,
    const bf16x8 (&qf)[2], u16* Psw,
    f32x4 (&accO)[4], float& m, float& l, int lr, int lg) {
  f32x4 sacc[4] = {};
  __builtin_amdgcn_s_setprio(1);
#pragma unroll
  for (int n = 0; n < 4; ++n)
#pragma unroll
    for (int kk = 0; kk < 2; ++kk) {
      const int gsw = ((((kk << 2) | lg) ^ (lr & 7)) << 3);
      bf16x8 kf = *(const bf16x8*)&kb[(n * 16 + lr) * 64 + gsw];
      sacc[n] = __builtin_amdgcn_mfma_f32_16x16x32_bf16(kf, qf[kk], sacc[n], 0, 0, 0);
    }
  __builtin_amdgcn_s_setprio(0);
  if (MASKED) {
#pragma unroll
    for (int n = 0; n < 4; ++n)
#pragma unroll
      for (int j = 0; j < 4; ++j) {
        const int c = kv0 + n * 16 + lg * 4 + j;
        if (c > qrow) sacc[n][j] = -1e30f;
      }
  }
  u16x4 pk[4];
  softmax_rs(sacc, m, l, accO, pk);
  // store P row (q = lr): 16B-pair position = pair ^ (lr&7); half = granule&1
#pragma unroll
  for (int n = 0; n < 4; ++n) {
    const int g = n * 4 + lg;
    const int off = ((((g >> 1) ^ (lr & 7)) << 3) | ((g & 1) << 2));
    *(u16x4*)&Psw[lr * 64 + off] = pk[n];
  }
  __builtin_amdgcn_s_setprio(1);
#pragma unroll
  for (int kk = 0; kk < 2; ++kk) {
    const int po = (((kk * 4 + lg) ^ (lr & 7)) << 3);
    bf16x8 pb = *(const bf16x8*)&Psw[lr * 64 + po];  // P[q=lr][kk*32+lg*8..+8]
#pragma unroll
    for (int db = 0; db < 4; ++db) {
      const int gsw = ((((kk << 2) | lg) ^ (lr & 7)) << 3);
      bf16x8 vf = *(const bf16x8*)&vb[(db * 16 + lr) * 64 + gsw];
      accO[db] = __builtin_amdgcn_mfma_f32_16x16x32_bf16(vf, pb, accO[db], 0, 0, 0);
    }
  }
  __builtin_amdgcn_s_setprio(0);
}

// grid (B*16 heads, 32 bands heavy-first), 256 thr = 4 waves x 16 q-rows.
// 1024 blocks = 4/CU all-resident, 16 waves/CU.
__global__ __launch_bounds__(256, 4)
void flash_attn_kernel(const u16* __restrict__ Q, const u16* __restrict__ K,
                       const u16* __restrict__ Vt, u16* __restrict__ O) {
  __shared__ __align__(16) u16 Klds[2][64 * 64];
  __shared__ __align__(16) u16 Vlds[2][64 * 64];
  __shared__ __align__(16) u16 Ps[4][16 * 64];
  const int bh = blockIdx.x;
  const int qcb = 31 - (int)blockIdx.y;    // heavy-first
  const int b = bh >> 4, h = bh & 15;
  const int tid = threadIdx.x;
  const int wv = tid >> 6, lane = tid & 63;
  const int lr = lane & 15, lg = lane >> 4;
  const int qbase = qcb * 64 + wv * 16;
  const int qrow = qbase + lr;             // this lane's q-row
  const size_t hb = (size_t)bh * (2048 * 64);
  const u16* Qh = Q + hb;

  // staging pointers advanced incrementally; wave stages 16 rows of K + V.
  const int sgr = ((lane & 7) ^ (lane >> 3)) << 3;  // pre-swizzled src granule
  const int srw = lane >> 3;                        // 0..7
  const u16* kp = K + hb + (size_t)(wv * 16 + srw) * 64 + sgr;
  const u16* vp = Vt + hb + (size_t)(wv * 16 + srw) * 2048 + sgr;
  const int ldso = (wv * 16) * 64;
  auto STAGE = [&](const u16* kq, const u16* vq, int bufi) {
    u16* kbd = Klds[bufi] + ldso;
    u16* vbd = Vlds[bufi] + ldso;
    glds16(kq, kbd);
    glds16(kq + 8 * 64, kbd + 8 * 64);
    glds16(vq, vbd);
    glds16(vq + 8 * 2048, vbd + 8 * 64);
  };

  bf16x8 qf[2];
#pragma unroll
  for (int kk = 0; kk < 2; ++kk)
    qf[kk] = *(const bf16x8*)(Qh + (size_t)qrow * 64 + kk * 32 + lg * 8);

  f32x4 accO[4] = {};
  float m = -1e30f, l = 0.f;

  const int nt = qcb + 1;                  // tiles incl. the masked diagonal
  STAGE(kp, vp, 0);
  kp += 64 * 64; vp += 64;
  __syncthreads();                         // drain stage-0, all waves ready
  for (int t = 0; t < nt - 1; ++t) {
    STAGE(kp, vp, (t & 1) ^ 1);            // prefetch next into other buffer
    kp += 64 * 64; vp += 64;
    attn_tile<false>(Klds[t & 1], Vlds[t & 1], t * 64, qrow, qf, Ps[wv],
                     accO, m, l, lr, lg);
    __syncthreads();                       // drain prefetch + lds reads
  }
  attn_tile<true>(Klds[(nt - 1) & 1], Vlds[(nt - 1) & 1], (nt - 1) * 64, qrow,
                  qf, Ps[wv], accO, m, l, lr, lg);

  const float inv = 1.0f / l;
#pragma unroll
  for (int db = 0; db < 4; ++db) {
    u16x4 pk;
#pragma unroll
    for (int j = 0; j < 4; ++j) pk[j] = f2bf(accO[db][j] * inv);
    const int d = db * 16 + lg * 4;
    *(u16x4*)&O[((size_t)(b * 2048 + qrow) * 16 + h) * 64 + d] = pk;
  }
}

// ------------------------------------------------------------ output projection
template<bool WF32>
__global__ __launch_bounds__(256, 2)
void out_gemm_kernel(const u16* __restrict__ A, const void* __restrict__ W,
                     float* __restrict__ out) {
  __shared__ __align__(16) u16 As[128 * 64];
  __shared__ __align__(16) u16 Bs[128 * 64];
  const int m0 = blockIdx.x * 128, n0 = blockIdx.y * 128;
  f32x4 acc[4][4] = {};
  gemm128_core<false, WF32>(A, W, As, Bs, m0, n0, acc);
  const int lane = threadIdx.x & 63, wave = threadIdx.x >> 6;
  const int wr = (wave >> 1) * 64, wc = (wave & 1) * 64;
  const int lr = lane & 15, lg = lane >> 4;
#pragma unroll
  for (int i = 0; i < 4; ++i)
#pragma unroll
    for (int n = 0; n < 4; ++n) {
      const int c = n0 + wc + n * 16 + lr;
#pragma unroll
      for (int j = 0; j < 4; ++j) {
        const int r = m0 + wr + i * 16 + lg * 4 + j;
        out[(size_t)r * 1024 + c] = acc[i][n][j];   // f32 store, no rounding
      }
    }
}

// --------------------------------------------------------------------- launch
extern "C" void kernel_launch(void* const* d_in, const int* in_sizes, int n_in,
                              void* d_out, int out_size, void* d_ws, size_t ws_size,
                              hipStream_t stream) {
  const float* x  = (const float*)d_in[0];
  const int*   tp = (const int*)d_in[1];
  const float* Wq = (const float*)d_in[2];
  const float* Wk = (const float*)d_in[3];
  const float* Wv = (const float*)d_in[4];
  const float* Wo = (const float*)d_in[5];
  float* out = (float*)d_out;
  const int B = in_sizes[0] / (2048 * 1024);
  const size_t xel = (size_t)B * 2048 * 1024;        // X elements
  const size_t tsz = xel * sizeof(u16);              // 8MB @ B=2
  const size_t TBL = 2048 * 32 * 2 * sizeof(float);  // cos+sin tables
  // Q,K (bf16) live inside d_out (f32 out = 2*tsz bytes); consumed by flash
  // before out_gemm overwrites. Vt, Ob, tables (+ bf16 copies) in ws.
  u16* Qb = (u16*)d_out;
  u16* Kb = (u16*)((char*)d_out + tsz);
  char* ws = (char*)d_ws;
  u16* Vt = (u16*)(ws);
  u16* Ob = (u16*)(ws + tsz);
  float* cosT = (float*)(ws + 2 * tsz);
  float* sinT = cosT + 2048 * 32;
  u16* Xb  = (u16*)(ws + 2 * tsz + TBL);
  u16* Wb4 = Xb + xel;                               // Wq|Wk|Wv|Wo bf16
  const size_t need = 2 * tsz + TBL + tsz + 4 * (size_t)(1024 * 1024) * sizeof(u16);
  const bool cvt = ws_size >= need;
  const size_t xn8 = xel / 8;                        // 8-elem groups in X
  const int xplanes = (int)((xn8 + 512 * 256 - 1) / (512 * 256));

  if (cvt) {
    prep_kernel<<<dim3(512, 1, 5 + xplanes), dim3(256), 0, stream>>>(
        Wq, Wk, Wv, Wo, Wb4, x, Xb, xn8, tp, cosT, sinT);
    qkv_gemm_kernel<false><<<dim3(B * 16, 8, 3), dim3(256), 0, stream>>>(
        Xb, Wb4, Wb4 + 1024 * 1024, Wb4 + 2 * 1024 * 1024, cosT, sinT, Qb, Kb, Vt);
  } else {
    prep_kernel<<<dim3(512, 1, 5), dim3(256), 0, stream>>>(
        Wq, Wk, Wv, Wo, Wb4, x, Xb, 0, tp, cosT, sinT);  // tables via z=4
    qkv_gemm_kernel<true><<<dim3(B * 16, 8, 3), dim3(256), 0, stream>>>(
        x, Wq, Wk, Wv, cosT, sinT, Qb, Kb, Vt);
  }
  flash_attn_kernel<<<dim3(B * 16, 32), dim3(256), 0, stream>>>(Qb, Kb, Vt, Ob);
  if (cvt) {
    out_gemm_kernel<false><<<dim3(B * 16, 8), dim3(256), 0, stream>>>(
        Ob, Wb4 + 3 * 1024 * 1024, out);
  } else {
    out_gemm_kernel<true><<<dim3(B * 16, 8), dim3(256), 0, stream>>>(Ob, Wo, out);
  }
}